// Round 4
// baseline (214.297 us; speedup 1.0000x reference)
//
#include <hip/hip_runtime.h>
#include <stdint.h>

#define F 256
#define R 64                    // rows per block
#define THREADS 256
#define GCH 32                  // g-rows per W chunk (conv layout, verified R0/R1/R2)
#define NCH (F / GCH)           // 8 chunks
#define CH_SLOTS (GCH * F / 8)  // 1024 16B slots per chunk

typedef __attribute__((ext_vector_type(8))) short short8;
typedef __attribute__((ext_vector_type(4))) float floatx4;

// Single-instruction rotate: alignbit(x,x,32-d) == rotl(x,d).
__device__ __forceinline__ uint32_t rotl32(uint32_t x, int d) {
  return __builtin_amdgcn_alignbit(x, x, (uint32_t)(32 - d));
}

// Threefry keys + hoisted round-injection constants (verified R1/R2).
struct TFK { uint32_t k0, k1, k2, a1, a2, a3, a4, a5; };

__device__ __forceinline__ TFK mkkeys(uint32_t k0, uint32_t k1) {
  TFK K;
  K.k0 = k0; K.k1 = k1; K.k2 = k0 ^ k1 ^ 0x1BD11BDAu;
  K.a1 = K.k2 + 1u; K.a2 = k0 + 2u; K.a3 = k1 + 3u;
  K.a4 = K.k2 + 4u; K.a5 = k0 + 5u;
  return K;
}

// Single-chain threefry2x32 (20 rounds) — fold_in, once per thread (verified R2).
__device__ __forceinline__ void tf_one(const TFK& K, uint32_t& x0, uint32_t& x1) {
  x0 += K.k0; x1 += K.k1;
#define TF1(r) x0 += x1; x1 = rotl32(x1, r); x1 ^= x0;
  TF1(13) TF1(15) TF1(26) TF1(6)   x0 += K.k1; x1 += K.a1;
  TF1(17) TF1(29) TF1(16) TF1(24)  x0 += K.k2; x1 += K.a2;
  TF1(13) TF1(15) TF1(26) TF1(6)   x0 += K.k0; x1 += K.a3;
  TF1(17) TF1(29) TF1(16) TF1(24)  x0 += K.k1; x1 += K.a4;
  TF1(13) TF1(15) TF1(26) TF1(6)   x0 += K.k2; x1 += K.a5;
#undef TF1
}

// Dual-chain threefry: counters i, i+1 in manually interleaved lockstep
// (verified R1/R2).
__device__ __forceinline__ void tf_pair(const TFK& K, uint32_t i,
                                        uint32_t& oa, uint32_t& ob) {
  uint32_t a0 = K.k0, a1 = K.k1 + i;
  uint32_t b0 = K.k0, b1 = K.k1 + i + 1u;
#define TF2(r)  a0 += a1; b0 += b1;                         \
                a1 = rotl32(a1, r); b1 = rotl32(b1, r);     \
                a1 ^= a0; b1 ^= b0;
#define INJ2(u, v) a0 += (u); b0 += (u); a1 += (v); b1 += (v);
  TF2(13) TF2(15) TF2(26) TF2(6)   INJ2(K.k1, K.a1)
  TF2(17) TF2(29) TF2(16) TF2(24)  INJ2(K.k2, K.a2)
  TF2(13) TF2(15) TF2(26) TF2(6)   INJ2(K.k0, K.a3)
  TF2(17) TF2(29) TF2(16) TF2(24)  INJ2(K.k1, K.a4)
  TF2(13) TF2(15) TF2(26) TF2(6)   INJ2(K.k2, K.a5)
#undef TF2
#undef INJ2
  oa = a0 ^ a1;
  ob = b0 ^ b1;
}

// Two features (counters i, i+1) -> packed bf16 pair (verified R1/R2).
// 2.3283064365386963e-8 IS 100*2^-32 (do NOT multiply by 100 again), RNE
// round, v_perm pack == (ulo>>16)|((uhi>>16)<<16).
__device__ __forceinline__ uint32_t featpack(const TFK& K, uint32_t i) {
  uint32_t xa, xb;
  tf_pair(K, i, xa, xb);
  uint32_t ulo = __float_as_uint((float)xa * 2.3283064365386963e-8f);
  uint32_t uhi = __float_as_uint((float)xb * 2.3283064365386963e-8f);
  ulo += 0x7FFFu + ((ulo >> 16) & 1u);
  uhi += 0x7FFFu + ((uhi >> 16) & 1u);
  return __builtin_amdgcn_perm(uhi, ulo, 0x07060302u);
}

// One A-fragment (8 features = 4 pairs) for features fb..fb+7 (verified R2).
__device__ __forceinline__ short8 quad(const TFK& K, uint32_t fb) {
  uint32_t w32[4];
  #pragma unroll
  for (int p = 0; p < 4; ++p) w32[p] = featpack(K, fb + 2u * p);
  union { uint32_t w[4]; short8 s; } u;
  u.w[0] = w32[0]; u.w[1] = w32[1]; u.w[2] = w32[2]; u.w[3] = w32[3];
  return u.s;
}

// fp32 -> bf16 RNE (conv kernel only)
__device__ __forceinline__ uint32_t f2bf(float f) {
  uint32_t u = __float_as_uint(f);
  u += 0x7FFFu + ((u >> 16) & 1u);
  return u >> 16;
}

// One-time: W fp32 -> bf16 TRANSPOSED into slot order — EXACT copy of the
// verified R0/R1/R2 G-chunk layout. Slot s: chunk gt=s>>10, c=(s>>5)&31
// (k-granule), g=s&31. Holds W[gt*32+g][c*8 .. c*8+7] as 8 bf16.
__global__ __launch_bounds__(256) void femb_conv(const float* __restrict__ W,
                                                 uint16_t* __restrict__ ws) {
  int s = blockIdx.x * 256 + threadIdx.x;   // 8192 slots
  int gt = s >> 10;
  int c = (s >> 5) & 31;
  int g = s & 31;
  const float4* src = (const float4*)(W + (size_t)(gt * GCH + g) * F + c * 8);
  float4 v0 = src[0], v1 = src[1];
  short8 o;
  o[0] = (short)f2bf(v0.x); o[1] = (short)f2bf(v0.y);
  o[2] = (short)f2bf(v0.z); o[3] = (short)f2bf(v0.w);
  o[4] = (short)f2bf(v1.x); o[5] = (short)f2bf(v1.y);
  o[6] = (short)f2bf(v1.z); o[7] = (short)f2bf(v1.w);
  *(short8*)(ws + (size_t)s * 8) = o;
}

// Loop-interchanged no-LDS main (pure reorder of the PASSING R1 kernel):
// kt outer, n'=0..15 inner with gt=n'>>1, n=n'&1 — the (address, afrag, acc,
// store) tuples are bit-identical to R1's, only reordered; per-acc
// accumulation order over kt is preserved. New vs R1: (a) stores hoisted to
// one end burst (same addresses/values), (b) the NEXT chunk's A-fragment is
// computed inside the chunk body in two featpack halves, each (~620 cyc of
// VALU) covering one 8-load group's L2 latency (~200-400 cyc). No LDS, no
// barriers, no DMA -> waves free-run and phases mix across waves/blocks.
__global__ __launch_bounds__(THREADS, 3) void femb_main(
    const float* __restrict__ x, const uint16_t* __restrict__ Wbf,
    const float* __restrict__ bias, float* __restrict__ out) {
  const int tid  = threadIdx.x;
  const int lane = tid & 63;
  const int wave = tid >> 6;
  const int qd   = lane >> 4;
  const int l16  = lane & 15;
  const size_t row0 = (size_t)blockIdx.x * R;
  const int myrow = (int)row0 + wave * 16 + l16;

  float xv = x[myrow];

  // fold_in: key = threefry((0,42), (0, bitcast(x))). 4x redundant across qd.
  const TFK K42 = mkkeys(0u, 42u);
  uint32_t u0 = 0u, u1 = __float_as_uint(xv);
  tf_one(K42, u0, u1);
  const TFK K = mkkeys(u0, u1);

  // A-fragment for chunk 0: lane (qd,l16) owns A[m=l16][k=qd*8+j],
  // features kt*32 + qd*8 + j for row wave*16+l16.
  short8 afragC = quad(K, (uint32_t)(qd * 8));

  // Per-lane W base (uint16 units). Chunk kt, tile n' reads 16B at
  //   (n'>>1)*8192 + (n'&1)*128 + kt*1024 + qd*256 + l16*8
  // == R1's (gt*CH_SLOTS*8) + ((kt*4+qd)*32 + n*16 + l16)*8 with gt=n'>>1,
  // n=n'&1 — identical address set, reordered.
  const uint16_t* wlane = Wbf + (size_t)(qd * 256 + l16 * 8);

  floatx4 acc[16];
  #pragma unroll
  for (int n = 0; n < 16; ++n) acc[n] = (floatx4){0.f, 0.f, 0.f, 0.f};

  #pragma unroll 1
  for (int kt = 0; kt < NCH; ++kt) {
    const uint16_t* wk = wlane + (size_t)kt * 1024;
    const uint32_t fb = (uint32_t)((kt + 1) * GCH + qd * 8);
    const bool more = (kt + 1 < NCH);
    uint32_t w0 = 0, w1 = 0, w2 = 0, w3 = 0;
    short8 b[8];

    // half A: issue 8 loads, burn 2 featpacks under their latency, then MFMA
    #pragma unroll
    for (int n = 0; n < 8; ++n)
      b[n] = *(const short8*)(wk + (n >> 1) * 8192 + (n & 1) * 128);
    if (more) { w0 = featpack(K, fb); w1 = featpack(K, fb + 2u); }
    #pragma unroll
    for (int n = 0; n < 8; ++n)
      acc[n] = __builtin_amdgcn_mfma_f32_16x16x32_bf16(afragC, b[n], acc[n],
                                                       0, 0, 0);

    // half B: tiles 8..15
    #pragma unroll
    for (int n = 0; n < 8; ++n)
      b[n] = *(const short8*)(wk + ((n + 8) >> 1) * 8192 + (n & 1) * 128);
    if (more) { w2 = featpack(K, fb + 4u); w3 = featpack(K, fb + 6u); }
    #pragma unroll
    for (int n = 0; n < 8; ++n)
      acc[n + 8] = __builtin_amdgcn_mfma_f32_16x16x32_bf16(afragC, b[n],
                                                           acc[n + 8], 0, 0, 0);

    if (more) {
      union { uint32_t w[4]; short8 s; } u;
      u.w[0] = w0; u.w[1] = w1; u.w[2] = w2; u.w[3] = w3;
      afragC = u.s;
    }
  }

  // Epilogue: D[row=qd*4+reg][col=l16] per n-tile (m89-verified layout);
  // acc[n'] holds g = n'*16 + l16 == R1's gt*32 + n*16 + l16. One store
  // burst — its drain overlaps other waves'/blocks' RNG (no barriers here).
  const size_t growbase = row0 + (size_t)(wave * 16 + qd * 4);
  #pragma unroll
  for (int n = 0; n < 16; ++n) {
    int g = n * 16 + l16;
    float bg = bias[g];
    #pragma unroll
    for (int reg = 0; reg < 4; ++reg)
      out[(growbase + reg) * F + g] = acc[n][reg] + bg;
  }
}

extern "C" void kernel_launch(void* const* d_in, const int* in_sizes, int n_in,
                              void* d_out, int out_size, void* d_ws, size_t ws_size,
                              hipStream_t stream) {
  const float* x = (const float*)d_in[0];
  const float* W = (const float*)d_in[1];
  const float* b = (const float*)d_in[2];
  float* out = (float*)d_out;
  uint16_t* wsbf = (uint16_t*)d_ws;          // 128 KB of ws_size
  const int nrows = in_sizes[0];             // 131072
  const int blocks = nrows / R;              // 2048

  hipLaunchKernelGGL(femb_conv, dim3((F * F / 8) / 256), dim3(256), 0, stream, W, wsbf);
  hipLaunchKernelGGL(femb_main, dim3(blocks), dim3(THREADS), 0, stream,
                     x, wsbf, b, out);
}

// Round 6
// 189.721 us; speedup vs baseline: 1.1295x; 1.1295x over previous
//
#include <hip/hip_runtime.h>
#include <stdint.h>

#define F 256
#define R 64                    // rows per block
#define THREADS 256
#define GCH 32                  // g-rows per staged W chunk
#define NCH (F / GCH)           // 8 chunks
#define CH_SLOTS (GCH * F / 8)  // 1024 16B slots per chunk
#define NBUF 3                  // LDS buffers (depth-2 prefetch, counted vmcnt)

typedef __attribute__((ext_vector_type(8))) short short8;
typedef __attribute__((ext_vector_type(4))) float floatx4;

// Single-instruction rotate: alignbit(x,x,32-d) == rotl(x,d).
__device__ __forceinline__ uint32_t rotl32(uint32_t x, int d) {
  return __builtin_amdgcn_alignbit(x, x, (uint32_t)(32 - d));
}

// Threefry keys + hoisted round-injection constants (verified R0-R2).
struct TFK { uint32_t k0, k1, k2, a1, a2, a3, a4, a5; };

__device__ __forceinline__ TFK mkkeys(uint32_t k0, uint32_t k1) {
  TFK K;
  K.k0 = k0; K.k1 = k1; K.k2 = k0 ^ k1 ^ 0x1BD11BDAu;
  K.a1 = K.k2 + 1u; K.a2 = k0 + 2u; K.a3 = k1 + 3u;
  K.a4 = K.k2 + 4u; K.a5 = k0 + 5u;
  return K;
}

// Single-chain threefry2x32 (20 rounds) — fold_in, once per thread.
__device__ __forceinline__ void tf_one(const TFK& K, uint32_t& x0, uint32_t& x1) {
  x0 += K.k0; x1 += K.k1;
#define TF1(r) x0 += x1; x1 = rotl32(x1, r); x1 ^= x0;
  TF1(13) TF1(15) TF1(26) TF1(6)   x0 += K.k1; x1 += K.a1;
  TF1(17) TF1(29) TF1(16) TF1(24)  x0 += K.k2; x1 += K.a2;
  TF1(13) TF1(15) TF1(26) TF1(6)   x0 += K.k0; x1 += K.a3;
  TF1(17) TF1(29) TF1(16) TF1(24)  x0 += K.k1; x1 += K.a4;
  TF1(13) TF1(15) TF1(26) TF1(6)   x0 += K.k2; x1 += K.a5;
#undef TF1
}

// Dual-chain threefry: counters i, i+1 in manually interleaved lockstep.
__device__ __forceinline__ void tf_pair(const TFK& K, uint32_t i,
                                        uint32_t& oa, uint32_t& ob) {
  uint32_t a0 = K.k0, a1 = K.k1 + i;
  uint32_t b0 = K.k0, b1 = K.k1 + i + 1u;
#define TF2(r)  a0 += a1; b0 += b1;                         \
                a1 = rotl32(a1, r); b1 = rotl32(b1, r);     \
                a1 ^= a0; b1 ^= b0;
#define INJ2(u, v) a0 += (u); b0 += (u); a1 += (v); b1 += (v);
  TF2(13) TF2(15) TF2(26) TF2(6)   INJ2(K.k1, K.a1)
  TF2(17) TF2(29) TF2(16) TF2(24)  INJ2(K.k2, K.a2)
  TF2(13) TF2(15) TF2(26) TF2(6)   INJ2(K.k0, K.a3)
  TF2(17) TF2(29) TF2(16) TF2(24)  INJ2(K.k1, K.a4)
  TF2(13) TF2(15) TF2(26) TF2(6)   INJ2(K.k2, K.a5)
#undef TF2
#undef INJ2
  oa = a0 ^ a1;
  ob = b0 ^ b1;
}

// Two features (counters i, i+1) -> packed bf16 pair. Bit-identical numerics:
// 2.3283064365386963e-8 IS 100*2^-32 (do NOT multiply by 100 again), RNE
// round, v_perm pack == (ulo>>16)|((uhi>>16)<<16).
__device__ __forceinline__ uint32_t featpack(const TFK& K, uint32_t i) {
  uint32_t xa, xb;
  tf_pair(K, i, xa, xb);
  uint32_t ulo = __float_as_uint((float)xa * 2.3283064365386963e-8f);
  uint32_t uhi = __float_as_uint((float)xb * 2.3283064365386963e-8f);
  ulo += 0x7FFFu + ((ulo >> 16) & 1u);
  uhi += 0x7FFFu + ((uhi >> 16) & 1u);
  return __builtin_amdgcn_perm(uhi, ulo, 0x07060302u);
}

// One A-fragment (8 features = 4 pairs) for features fb..fb+7.
__device__ __forceinline__ short8 quad(const TFK& K, uint32_t fb) {
  uint32_t w32[4];
  #pragma unroll
  for (int p = 0; p < 4; ++p) w32[p] = featpack(K, fb + 2u * p);
  union { uint32_t w[4]; short8 s; } u;
  u.w[0] = w32[0]; u.w[1] = w32[1]; u.w[2] = w32[2]; u.w[3] = w32[3];
  return u.s;
}

// fp32 -> bf16 RNE (conv kernel only)
__device__ __forceinline__ uint32_t f2bf(float f) {
  uint32_t u = __float_as_uint(f);
  u += 0x7FFFu + ((u >> 16) & 1u);
  return u >> 16;
}

__device__ __forceinline__ void gl_lds16(const void* gptr, void* lptr) {
  __builtin_amdgcn_global_load_lds(
      (const __attribute__((address_space(1))) uint32_t*)gptr,
      (__attribute__((address_space(3))) uint32_t*)lptr, 16, 0, 0);
}

// DMA one 16 KB W chunk into LDS (wave-uniform base + lane*16B, R0-verified).
__device__ __forceinline__ void dma_chunk(const uint16_t* __restrict__ src,
                                          uint16_t* dst, int wave, int lane) {
  #pragma unroll
  for (int it = 0; it < CH_SLOTS / THREADS; ++it) {
    int sbase = it * THREADS + wave * 64;
    gl_lds16(src + (size_t)(sbase + lane) * 8, dst + (size_t)sbase * 8);
  }
}

// One-time: W fp32 -> bf16 TRANSPOSED into DMA slot order — EXACT R0 layout.
// Slot s: chunk gt=s>>10, c=(s>>5)&31 (k-granule), g=s&31.
// Holds W[gt*32+g][c*8 .. c*8+7] as 8 bf16.
__global__ __launch_bounds__(256) void femb_conv(const float* __restrict__ W,
                                                 uint16_t* __restrict__ ws) {
  int s = blockIdx.x * 256 + threadIdx.x;   // 8192 slots
  int gt = s >> 10;
  int c = (s >> 5) & 31;
  int g = s & 31;
  const float4* src = (const float4*)(W + (size_t)(gt * GCH + g) * F + c * 8);
  float4 v0 = src[0], v1 = src[1];
  short8 o;
  o[0] = (short)f2bf(v0.x); o[1] = (short)f2bf(v0.y);
  o[2] = (short)f2bf(v0.z); o[3] = (short)f2bf(v0.w);
  o[4] = (short)f2bf(v1.x); o[5] = (short)f2bf(v1.y);
  o[6] = (short)f2bf(v1.z); o[7] = (short)f2bf(v1.w);
  *(short8*)(ws + (size_t)s * 8) = o;
}

// R0 structure + two stall-removal edits:
//  (1) stores deferred to one end burst (acc[16]) — stores leave the vmcnt
//      queue, so no barrier ever waits on them;
//  (2) 3-buffer LDS, raw s_barrier with COUNTED s_waitcnt vmcnt(4) (T3/T4):
//      chunk gt+1's DMA stays in flight across the barrier; DMA(gt+2) is
//      issued right after the barrier (its target buf's readers just synced).
// Data mappings (conv layout, A-frag, LDS slots, m89 store layout, RNG) are
// byte-identical to the verified R0 kernel.
__global__ __launch_bounds__(THREADS, 3) void femb_main(
    const float* __restrict__ x, const uint16_t* __restrict__ Wbf,
    const float* __restrict__ bias, float* __restrict__ out) {
  __shared__ uint16_t sW[NBUF][GCH * F];   // 3 x 16 KB

  const int tid  = threadIdx.x;
  const int lane = tid & 63;
  const int wave = tid >> 6;
  const int qd   = lane >> 4;
  const int l16  = lane & 15;
  const size_t row0 = (size_t)blockIdx.x * R;
  const int myrow = (int)row0 + wave * 16 + l16;

  // x first so its waitcnt doesn't queue behind the DMA.
  float xv = x[myrow];

  // Prefetch chunks 0 and 1 (8 loads/wave outstanding) — the ~10K-cycle RNG
  // burn below completely hides them; iter-0's vmcnt wait is a no-op.
  dma_chunk(Wbf, sW[0], wave, lane);
  dma_chunk(Wbf + (size_t)CH_SLOTS * 8, sW[1], wave, lane);

  // Bias prefetch (epilogue operands), L2-hot, hidden under RNG too.
  float bgv[16];
  #pragma unroll
  for (int n = 0; n < 16; ++n) bgv[n] = bias[n * 16 + l16];

  // fold_in: key = threefry((0,42), (0, bitcast(x))). 4x redundant across qd.
  const TFK K42 = mkkeys(0u, 42u);
  uint32_t u0 = 0u, u1 = __float_as_uint(xv);
  tf_one(K42, u0, u1);
  const TFK K = mkkeys(u0, u1);

  // RNG straight into A-fragments: lane (qd,l16) of wave w owns
  // A[m=l16][k=qd*8+j] for row w*16+l16 -> features kt*32+qd*8+j.
  short8 afrag[8];
  #pragma unroll
  for (int kt = 0; kt < 8; ++kt)
    afrag[kt] = quad(K, (uint32_t)(kt * 32 + qd * 8));

  floatx4 acc[16];
  #pragma unroll
  for (int n = 0; n < 16; ++n) acc[n] = (floatx4){0.f, 0.f, 0.f, 0.f};

  #pragma unroll
  for (int gt = 0; gt < NCH; ++gt) {
    // Pin prior MFMAs + their lgkmcnt on this side of the barrier (rule #18),
    // then wait only for MY chunk-gt DMA (4 oldest); chunk gt+1 stays in
    // flight. Every wave does this before the barrier, so after s_barrier all
    // waves' chunk-gt LDS writes are visible. Last iter has nothing newer
    // outstanding -> vmcnt(0) (still only 4 loads deep).
    __builtin_amdgcn_sched_barrier(0);
    if (gt == NCH - 1)
      asm volatile("s_waitcnt vmcnt(0) lgkmcnt(0)" ::: "memory");
    else
      asm volatile("s_waitcnt vmcnt(4) lgkmcnt(0)" ::: "memory");
    __builtin_amdgcn_s_barrier();
    __builtin_amdgcn_sched_barrier(0);

    // DMA chunk gt+2 into buf (gt+2)%3: its previous readers (iter gt-1)
    // just synced at the barrier above; (gt,gt+1,gt+2) mod 3 are distinct.
    if (gt + 2 < NCH)
      dma_chunk(Wbf + (size_t)(gt + 2) * CH_SLOTS * 8,
                sW[(gt + 2) % NBUF], wave, lane);

    const uint16_t* buf = sW[gt % NBUF];
    #pragma unroll
    for (int kt = 0; kt < 8; ++kt) {
      int c = kt * 4 + qd;
      #pragma unroll
      for (int n = 0; n < 2; ++n) {
        // slot = c*32 + n*16 + l16: 16 consecutive b128 per 16-lane group.
        short8 b = *(const short8*)&buf[(size_t)(c * 32 + n * 16 + l16) * 8];
        acc[gt * 2 + n] = __builtin_amdgcn_mfma_f32_16x16x32_bf16(
            afrag[kt], b, acc[gt * 2 + n], 0, 0, 0);
      }
    }
    // no stores here — deferred to the end burst
  }

  // Epilogue: D[row=qd*4+reg][col=l16] (m89-verified layout), one burst.
  // acc[gt*2+n] holds g = gt*32 + n*16 + l16 == n'*16 + l16 with n'=gt*2+n.
  const size_t growbase = row0 + (size_t)(wave * 16 + qd * 4);
  #pragma unroll
  for (int n = 0; n < 16; ++n) {
    int g = n * 16 + l16;
    #pragma unroll
    for (int reg = 0; reg < 4; ++reg)
      out[(growbase + reg) * F + g] = acc[n][reg] + bgv[n];
  }
}

extern "C" void kernel_launch(void* const* d_in, const int* in_sizes, int n_in,
                              void* d_out, int out_size, void* d_ws, size_t ws_size,
                              hipStream_t stream) {
  const float* x = (const float*)d_in[0];
  const float* W = (const float*)d_in[1];
  const float* b = (const float*)d_in[2];
  float* out = (float*)d_out;
  uint16_t* wsbf = (uint16_t*)d_ws;          // 128 KB of ws_size
  const int nrows = in_sizes[0];             // 131072
  const int blocks = nrows / R;              // 2048

  hipLaunchKernelGGL(femb_conv, dim3((F * F / 8) / 256), dim3(256), 0, stream, W, wsbf);
  hipLaunchKernelGGL(femb_main, dim3(blocks), dim3(THREADS), 0, stream,
                     x, wsbf, b, out);
}